// Round 16
// baseline (136.716 us; speedup 1.0000x reference)
//
#include <hip/hip_runtime.h>

// Problem constants (fixed by setup_inputs): N=2048, d=256, T=256, Q=64
#define NN   2048
#define DD   256
#define TT   256
#define NYC  16384           // T*Q flattened y columns
#define CHUNK_COLS 128
#define NCHUNK_XY 128        // 16384 / 128 cols per chunk
#define NCHUNK_XX 16         // 2048 / 128
#define NROWBLK   8          // 2048 / 256 rows per block

static constexpr float INV_TEMP = 1.0f / 0.3f;

typedef __bf16 bf16x8 __attribute__((ext_vector_type(8)));
typedef float  f32x4  __attribute__((ext_vector_type(4)));

// Frag-linear layout: for a matrix M[C][256] (bf16), fragment index
// j = (g*8 + ks)*64 + lane holds M[g*16 + (lane&15)][ks*32 + (lane>>4)*8 .. +7].
// A 16-col tile = 8 KB contiguous; staged to LDS it is already in ds_read
// fragment order (frag ks at lds ks*1024 + lane*16).

// ------------------------------------------------ convert + zero accumulators
__global__ void cvt_zero_kernel(const float* __restrict__ x, const float* __restrict__ y,
                                bf16x8* __restrict__ xfl, bf16x8* __restrict__ yfl,
                                float* __restrict__ acc /* 3*NN floats: Tot,Pxy,Pxx */) {
    const int tid0   = blockIdx.x * blockDim.x + threadIdx.x;
    const int stride = gridDim.x * blockDim.x;
    for (int j = tid0; j < 3 * NN; j += stride) acc[j] = 0.f;

    const int NXF = NN * DD / 8;          // 65536 x-fragments
    for (int j = tid0; j < NXF; j += stride) {
        const int gk  = j >> 6;           // g*8 + ks
        const int sub = j & 63;
        const int qq  = sub & 3;          // k-quad (lane>>4 in fragment space)
        const int cc  = (sub >> 2) & 15;  // col-within-16 (lane&15)
        const int col = ((gk >> 3) << 4) + cc;
        const int k0  = ((gk & 7) << 5) + (qq << 3);
        const float4* s = (const float4*)(x + (size_t)col * DD + k0);
        float4 v0 = s[0], v1 = s[1];
        bf16x8 o;
        o[0] = (__bf16)v0.x; o[1] = (__bf16)v0.y; o[2] = (__bf16)v0.z; o[3] = (__bf16)v0.w;
        o[4] = (__bf16)v1.x; o[5] = (__bf16)v1.y; o[6] = (__bf16)v1.z; o[7] = (__bf16)v1.w;
        xfl[(size_t)gk * 64 + qq * 16 + cc] = o;
    }
    const int NYF = NYC * DD / 8;         // 524288 y-fragments
    for (int j = tid0; j < NYF; j += stride) {
        const int gk  = j >> 6;
        const int sub = j & 63;
        const int qq  = sub & 3;
        const int cc  = (sub >> 2) & 15;
        const int col = ((gk >> 3) << 4) + cc;
        const int k0  = ((gk & 7) << 5) + (qq << 3);
        const float4* s = (const float4*)(y + (size_t)col * DD + k0);
        float4 v0 = s[0], v1 = s[1];
        bf16x8 o;
        o[0] = (__bf16)v0.x; o[1] = (__bf16)v0.y; o[2] = (__bf16)v0.z; o[3] = (__bf16)v0.w;
        o[4] = (__bf16)v1.x; o[5] = (__bf16)v1.y; o[6] = (__bf16)v1.z; o[7] = (__bf16)v1.w;
        yfl[(size_t)gk * 64 + qq * 16 + cc] = o;
    }
}

// ------------------------------------------------ stats (GEMM + exp + grouped sums)
// 1152 blocks (XCD-swizzled): 256-row block x 128-col chunk. 4 waves, each
// wave owns 64 rows (t=4): A panel = 128 VGPRs, B from LDS (16 transient).
// R15 lesson: t=2 left too many wave-slots touching the same bytes -- LDS-read
// pipe (~11.5us) and 300MB L2 traffic dominated; counted-vmcnt pipeline alone
// was only -4us. t=4 halves B refetch AND LDS-read slots, doubles MFMA per
// epilogue. ~230 regs fits launch_bounds(256,2) (R3's t=4 died at cap 128).
// Depth-3 stage + counted vmcnt + raw barriers carried over UNCHANGED.
__global__ __launch_bounds__(256, 2) void stats_kernel(
        const bf16x8* __restrict__ xfl, const bf16x8* __restrict__ yfl,
        const int* __restrict__ tid,
        float* __restrict__ Tot, float* __restrict__ Pxy,
        float* __restrict__ Pxx, float* __restrict__ diag) {
    __shared__ __align__(16) char bstage[4][8192];   // 4 x (16 cols x 256 K bf16)

    const int id    = blockIdx.x;
    // XCD swizzle: id = hi*64 + bx*8 + lo; lo = XCD, chunk = lo + 8*hi.
    const int chunk = (id & 7) + ((id >> 6) << 3);   // 0..143
    const int bx    = (id >> 3) & 7;                 // 0..7 row-block (256 rows)
    const int mode  = (chunk >= NCHUNK_XY);          // 0 = x@y^T, 1 = x@x^T
    const int colbase = (mode ? chunk - NCHUNK_XY : chunk) * CHUNK_COLS;
    const bf16x8* __restrict__ colfl = mode ? xfl : yfl;

    const int tix  = threadIdx.x;
    const int lane = tix & 63;
    const int w    = tix >> 6;
    const int c16  = lane & 15;
    const int q    = lane >> 4;
    const int rowbase = bx * 256 + w * 64;
    const int rowg    = rowbase >> 4;                // row16-group index

    const char* gbase = (const char*)colfl + ((size_t)(colbase >> 4)) * 8192 + tix * 16;
    const bool wantdiag = mode && (bx == (colbase >> 8));

    // Stage tile ct into LDS buffer (ct&3): 8 KB, 2 x 16 B per thread, linear.
#define STAGE(ct_)                                                                        \
    do {                                                                                  \
        const char* g_ = gbase + (size_t)(ct_) * 8192;                                    \
        __builtin_amdgcn_global_load_lds(                                                 \
            (const __attribute__((address_space(1))) void*)g_,                            \
            (__attribute__((address_space(3))) void*)&bstage[(ct_) & 3][tix * 16],        \
            16, 0, 0);                                                                    \
        __builtin_amdgcn_global_load_lds(                                                 \
            (const __attribute__((address_space(1))) void*)(g_ + 4096),                   \
            (__attribute__((address_space(3))) void*)&bstage[(ct_) & 3][4096 + tix * 16], \
            16, 0, 0);                                                                    \
    } while (0)
#define WAITV(n_) asm volatile("s_waitcnt vmcnt(" #n_ ")" ::: "memory")
#define BAR() __builtin_amdgcn_s_barrier()

    // Deep prefetch first -- everything below overlaps the stage latency.
    STAGE(0); STAGE(1); STAGE(2);

    // A fragments: 64 rows x K=256 resident in registers (128 VGPRs).
    bf16x8 a[4][8];
#pragma unroll
    for (int t = 0; t < 4; t++)
#pragma unroll
        for (int ks = 0; ks < 8; ks++)
            a[t][ks] = xfl[((size_t)(rowg + t) * 8 + ks) * 64 + lane];

    // Row track-ids packed 4x8-bit (tids < 256).
    int trow[4];
#pragma unroll
    for (int t = 0; t < 4; t++) {
        const int rb = rowbase + t * 16 + q * 4;
        trow[t] = tid[rb] | (tid[rb + 1] << 8) | (tid[rb + 2] << 16) | (tid[rb + 3] << 24);
    }

    // Column track-ids for all 8 tiles (static-indexed under full unroll).
    int ctid[8];
#pragma unroll
    for (int ct = 0; ct < 8; ct++) {
        const int col = colbase + ct * 16 + c16;
        ctid[ct] = mode ? tid[col] : (col & (TT - 1));
    }

    float tot[4][4] = {};
    float pos[4][4] = {};

    // COMPUTE(ct): 32 MFMA from bstage[ct&3] + exp/grouped-sum epilogue.
#define COMPUTE(ct_)                                                                       \
    do {                                                                                   \
        const char* lbase = &bstage[(ct_) & 3][0];                                         \
        f32x4 ac0 = {0.f, 0.f, 0.f, 0.f};                                                  \
        f32x4 ac1 = {0.f, 0.f, 0.f, 0.f};                                                  \
        f32x4 ac2 = {0.f, 0.f, 0.f, 0.f};                                                  \
        f32x4 ac3 = {0.f, 0.f, 0.f, 0.f};                                                  \
        _Pragma("unroll")                                                                  \
        for (int h = 0; h < 2; h++) {                                                      \
            bf16x8 bf[4];                                                                  \
            _Pragma("unroll")                                                              \
            for (int k = 0; k < 4; k++)                                                    \
                bf[k] = *(const bf16x8*)(lbase + (h * 4 + k) * 1024 + lane * 16);          \
            _Pragma("unroll")                                                              \
            for (int k = 0; k < 4; k++) {                                                  \
                ac0 = __builtin_amdgcn_mfma_f32_16x16x32_bf16(a[0][h * 4 + k], bf[k],      \
                                                              ac0, 0, 0, 0);               \
                ac1 = __builtin_amdgcn_mfma_f32_16x16x32_bf16(a[1][h * 4 + k], bf[k],      \
                                                              ac1, 0, 0, 0);               \
                ac2 = __builtin_amdgcn_mfma_f32_16x16x32_bf16(a[2][h * 4 + k], bf[k],      \
                                                              ac2, 0, 0, 0);               \
                ac3 = __builtin_amdgcn_mfma_f32_16x16x32_bf16(a[3][h * 4 + k], bf[k],      \
                                                              ac3, 0, 0, 0);               \
            }                                                                              \
        }                                                                                  \
        const int col = colbase + (ct_) * 16 + c16;                                        \
        _Pragma("unroll")                                                                  \
        for (int t = 0; t < 4; t++) {                                                      \
            const f32x4 acv = (t == 0) ? ac0 : (t == 1) ? ac1 : (t == 2) ? ac2 : ac3;      \
            const int rw0 = rowbase + t * 16 + q * 4;                                      \
            _Pragma("unroll")                                                              \
            for (int r = 0; r < 4; r++) {                                                  \
                const float val = __expf(acv[r] * INV_TEMP);                               \
                tot[t][r] += val;                                                          \
                pos[t][r] += (((trow[t] >> (8 * r)) & 255) == ctid[(ct_)]) ? val : 0.f;    \
                if (wantdiag && col == rw0 + r) diag[col] = val;                           \
            }                                                                              \
        }                                                                                  \
    } while (0)

    // Prologue wait: FIFO vmcnt -- everything but the 4 newest retired, so
    // stage 0 (oldest) and the A panel are in. Barrier publishes all slices.
    WAITV(4); BAR();

    STAGE(3); COMPUTE(0); WAITV(4); BAR();   // in flight after wait: stages 2,3
    STAGE(4); COMPUTE(1); WAITV(4); BAR();
    STAGE(5); COMPUTE(2); WAITV(4); BAR();
    STAGE(6); COMPUTE(3); WAITV(4); BAR();
    STAGE(7); COMPUTE(4); WAITV(4); BAR();
    COMPUTE(5); WAITV(2); BAR();
    COMPUTE(6); WAITV(0); BAR();
    COMPUTE(7);

#undef COMPUTE
#undef STAGE
#undef WAITV
#undef BAR

    // Reduce across the 16 column-lanes sharing (q, r); one atomic per row.
#pragma unroll
    for (int t = 0; t < 4; t++)
#pragma unroll
        for (int r = 0; r < 4; r++) {
            float aS = tot[t][r], p = pos[t][r];
#pragma unroll
            for (int off = 1; off < 16; off <<= 1) {
                aS += __shfl_xor(aS, off);
                p  += __shfl_xor(p, off);
            }
            if (c16 == 0) {
                const int row = rowbase + t * 16 + q * 4 + r;
                atomicAdd(&Tot[row], aS);
                atomicAdd(mode ? &Pxx[row] : &Pxy[row], p);
            }
        }
}

// ------------------------------------------------ finalize (reads 32 KB only)
__global__ void finalize_kernel(const float* __restrict__ Tot, const float* __restrict__ Pxy,
                                const float* __restrict__ Pxx, const float* __restrict__ diag,
                                const int* __restrict__ tid, float* __restrict__ out) {
    __shared__ float num_s[TT], den_s[TT];
    __shared__ int cnt_s[TT];
    const int t = threadIdx.x;  // 256 threads
    num_s[t] = 0.f; den_s[t] = 0.f; cnt_s[t] = 0;
    __syncthreads();
    for (int i = t; i < NN; i += 256) {
        float tt_ = Tot[i], pxy = Pxy[i], pxx = Pxx[i];
        float num = pxy + 0.5f * (pxx - diag[i]);
        float den = tt_ - pxy - pxx;
        int tr = tid[i];
        atomicAdd(&num_s[tr], num);
        atomicAdd(&den_s[tr], den);
        atomicAdd(&cnt_s[tr], 1);
    }
    __syncthreads();
    float lt = 0.f, pr = 0.f;
    if (cnt_s[t] > 0) {
        lt = -logf(num_s[t] / (den_s[t] + num_s[t]));
        pr = 1.f;
    }
    for (int off = 32; off; off >>= 1) { lt += __shfl_down(lt, off); pr += __shfl_down(pr, off); }
    __shared__ float ls[4], ps[4];
    if ((t & 63) == 0) { ls[t >> 6] = lt; ps[t >> 6] = pr; }
    __syncthreads();
    if (t == 0) out[0] = (ls[0] + ls[1] + ls[2] + ls[3]) / (ps[0] + ps[1] + ps[2] + ps[3]);
}

// ------------------------------------------------ launch
extern "C" void kernel_launch(void* const* d_in, const int* in_sizes, int n_in,
                              void* d_out, int out_size, void* d_ws, size_t ws_size,
                              hipStream_t stream) {
    const float* x   = (const float*)d_in[0];
    const int*   tid = (const int*)d_in[1];
    const float* y   = (const float*)d_in[2];
    float* out = (float*)d_out;

    char* ws = (char*)d_ws;
    bf16x8* xfl = (bf16x8*)ws;                       // 1 MB frag-linear x
    bf16x8* yfl = (bf16x8*)(ws + (1u << 20));        // 8 MB frag-linear y
    float* acc  = (float*)(ws + 9u * (1u << 20));    // Tot,Pxy,Pxx,diag: 4*2048 f32
    float* Tot  = acc;
    float* Pxy  = acc + NN;
    float* Pxx  = acc + 2 * NN;
    float* diag = acc + 3 * NN;                      // fully rewritten by stats (mode 1)

    cvt_zero_kernel<<<2304, 256, 0, stream>>>(x, y, xfl, yfl, acc);
    stats_kernel<<<NROWBLK * (NCHUNK_XY + NCHUNK_XX), 256, 0, stream>>>(
        xfl, yfl, tid, Tot, Pxy, Pxx, diag);
    finalize_kernel<<<1, 256, 0, stream>>>(Tot, Pxy, Pxx, diag, tid, out);
}

// Round 17
// 106.914 us; speedup vs baseline: 1.2787x; 1.2787x over previous
//
#include <hip/hip_runtime.h>

// Problem constants (fixed by setup_inputs): N=2048, d=256, T=256, Q=64
#define NN   2048
#define DD   256
#define TT   256
#define NYC  16384           // T*Q flattened y columns
#define CHUNK_COLS 128
#define NCHUNK_XY 128        // 16384 / 128 cols per chunk
#define NCHUNK_XX 16         // 2048 / 128
#define NROWBLK   16         // 2048 / 128 rows per block

static constexpr float INV_TEMP = 1.0f / 0.3f;

typedef __bf16 bf16x8 __attribute__((ext_vector_type(8)));
typedef float  f32x4  __attribute__((ext_vector_type(4)));

// Frag-linear layout: for a matrix M[C][256] (bf16), fragment index
// j = (g*8 + ks)*64 + lane holds M[g*16 + (lane&15)][ks*32 + (lane>>4)*8 .. +7].
// A 16-col tile = 8 KB contiguous; staged to LDS it is already in ds_read
// fragment order (frag ks at lds ks*1024 + lane*16).

// ------------------------------------------------ convert + zero accumulators
__global__ void cvt_zero_kernel(const float* __restrict__ x, const float* __restrict__ y,
                                bf16x8* __restrict__ xfl, bf16x8* __restrict__ yfl,
                                float* __restrict__ acc /* 3*NN floats: Tot,Pxy,Pxx */) {
    const int tid0   = blockIdx.x * blockDim.x + threadIdx.x;
    const int stride = gridDim.x * blockDim.x;
    for (int j = tid0; j < 3 * NN; j += stride) acc[j] = 0.f;

    const int NXF = NN * DD / 8;          // 65536 x-fragments
    for (int j = tid0; j < NXF; j += stride) {
        const int gk  = j >> 6;           // g*8 + ks
        const int sub = j & 63;
        const int qq  = sub & 3;          // k-quad (lane>>4 in fragment space)
        const int cc  = (sub >> 2) & 15;  // col-within-16 (lane&15)
        const int col = ((gk >> 3) << 4) + cc;
        const int k0  = ((gk & 7) << 5) + (qq << 3);
        const float4* s = (const float4*)(x + (size_t)col * DD + k0);
        float4 v0 = s[0], v1 = s[1];
        bf16x8 o;
        o[0] = (__bf16)v0.x; o[1] = (__bf16)v0.y; o[2] = (__bf16)v0.z; o[3] = (__bf16)v0.w;
        o[4] = (__bf16)v1.x; o[5] = (__bf16)v1.y; o[6] = (__bf16)v1.z; o[7] = (__bf16)v1.w;
        xfl[(size_t)gk * 64 + qq * 16 + cc] = o;
    }
    const int NYF = NYC * DD / 8;         // 524288 y-fragments
    for (int j = tid0; j < NYF; j += stride) {
        const int gk  = j >> 6;
        const int sub = j & 63;
        const int qq  = sub & 3;
        const int cc  = (sub >> 2) & 15;
        const int col = ((gk >> 3) << 4) + cc;
        const int k0  = ((gk & 7) << 5) + (qq << 3);
        const float4* s = (const float4*)(y + (size_t)col * DD + k0);
        float4 v0 = s[0], v1 = s[1];
        bf16x8 o;
        o[0] = (__bf16)v0.x; o[1] = (__bf16)v0.y; o[2] = (__bf16)v0.z; o[3] = (__bf16)v0.w;
        o[4] = (__bf16)v1.x; o[5] = (__bf16)v1.y; o[6] = (__bf16)v1.z; o[7] = (__bf16)v1.w;
        yfl[(size_t)gk * 64 + qq * 16 + cc] = o;
    }
}

// ------------------------------------------------ stats (GEMM + exp + grouped sums)
// 2304 blocks (XCD-swizzled). 4 waves/block, wave owns 32 rows (t=2).
// Measured ladder: t=2 sync-barrier 40us -> t=2 counted-vmcnt 35us (R15, best);
// t=4 reg (R3/R6) and t=4 LDS (R16) both SPILL (>256 true regs) -> 64+us.
// R16 lesson: register models under-estimate by 30-50; t=4 is dead here.
// This version = R15 skeleton (depth-3 stage, 4 LDS bufs, counted vmcnt(4),
// raw barriers -- ledger verified R13/R14) + T5: s_setprio(1) around the MFMA
// cluster. Rationale (m218b): with a counted-vmcnt phase split, waves are in
// DIFFERENT phases (ds_read / MFMA / exp-epilogue); prio-1 keeps the matrix
// pipe fed instead of round-robining into epilogue waves. Null on lockstep
// (m190), +21-25% with phase-split -- we now have the prerequisite.
__global__ __launch_bounds__(256, 3) void stats_kernel(
        const bf16x8* __restrict__ xfl, const bf16x8* __restrict__ yfl,
        const int* __restrict__ tid,
        float* __restrict__ Tot, float* __restrict__ Pxy,
        float* __restrict__ Pxx, float* __restrict__ diag) {
    __shared__ __align__(16) char bstage[4][8192];   // 4 x (16 cols x 256 K bf16)

    const int id    = blockIdx.x;
    // XCD swizzle: id = hi*128 + bx*8 + lo; lo = XCD, chunk = lo + 8*hi.
    const int chunk = (id & 7) + ((id >> 7) << 3);   // 0..143
    const int bx    = (id >> 3) & 15;                // 0..15 row-block
    const int mode  = (chunk >= NCHUNK_XY);          // 0 = x@y^T, 1 = x@x^T
    const int colbase = (mode ? chunk - NCHUNK_XY : chunk) * CHUNK_COLS;
    const bf16x8* __restrict__ colfl = mode ? xfl : yfl;

    const int tix  = threadIdx.x;
    const int lane = tix & 63;
    const int w    = tix >> 6;
    const int c16  = lane & 15;
    const int q    = lane >> 4;
    const int rowbase = bx * 128 + w * 32;
    const int rowg    = rowbase >> 4;                // row16-group index

    const char* gbase = (const char*)colfl + ((size_t)(colbase >> 4)) * 8192 + tix * 16;
    const bool wantdiag = mode && (bx == (colbase >> 7));

    // Stage tile ct into LDS buffer (ct&3): 8 KB, 2 x 16 B per thread, linear.
#define STAGE(ct_)                                                                        \
    do {                                                                                  \
        const char* g_ = gbase + (size_t)(ct_) * 8192;                                    \
        __builtin_amdgcn_global_load_lds(                                                 \
            (const __attribute__((address_space(1))) void*)g_,                            \
            (__attribute__((address_space(3))) void*)&bstage[(ct_) & 3][tix * 16],        \
            16, 0, 0);                                                                    \
        __builtin_amdgcn_global_load_lds(                                                 \
            (const __attribute__((address_space(1))) void*)(g_ + 4096),                   \
            (__attribute__((address_space(3))) void*)&bstage[(ct_) & 3][4096 + tix * 16], \
            16, 0, 0);                                                                    \
    } while (0)
#define WAITV(n_) asm volatile("s_waitcnt vmcnt(" #n_ ")" ::: "memory")
#define BAR() __builtin_amdgcn_s_barrier()

    // Deep prefetch first -- everything below overlaps the stage latency.
    STAGE(0); STAGE(1); STAGE(2);

    // A fragments: 32 rows x K=256 resident in registers (64 VGPRs).
    bf16x8 a[2][8];
#pragma unroll
    for (int t = 0; t < 2; t++)
#pragma unroll
        for (int ks = 0; ks < 8; ks++)
            a[t][ks] = xfl[((size_t)(rowg + t) * 8 + ks) * 64 + lane];

    // Row track-ids packed 4x8-bit (tids < 256).
    int trow[2];
#pragma unroll
    for (int t = 0; t < 2; t++) {
        const int rb = rowbase + t * 16 + q * 4;
        trow[t] = tid[rb] | (tid[rb + 1] << 8) | (tid[rb + 2] << 16) | (tid[rb + 3] << 24);
    }

    // Column track-ids for all 8 tiles (static-indexed under full unroll).
    int ctid[8];
#pragma unroll
    for (int ct = 0; ct < 8; ct++) {
        const int col = colbase + ct * 16 + c16;
        ctid[ct] = mode ? tid[col] : (col & (TT - 1));
    }

    float tot[2][4] = {};
    float pos[2][4] = {};

    // COMPUTE(ct): MFMA from bstage[ct&3] (prio 1) + exp/grouped-sum epilogue.
#define COMPUTE(ct_)                                                                       \
    do {                                                                                   \
        const char* lbase = &bstage[(ct_) & 3][0];                                         \
        f32x4 acc0 = {0.f, 0.f, 0.f, 0.f};                                                 \
        f32x4 acc1 = {0.f, 0.f, 0.f, 0.f};                                                 \
        __builtin_amdgcn_s_setprio(1);                                                     \
        _Pragma("unroll")                                                                  \
        for (int h = 0; h < 2; h++) {                                                      \
            bf16x8 bf[4];                                                                  \
            _Pragma("unroll")                                                              \
            for (int k = 0; k < 4; k++)                                                    \
                bf[k] = *(const bf16x8*)(lbase + (h * 4 + k) * 1024 + lane * 16);          \
            _Pragma("unroll")                                                              \
            for (int k = 0; k < 4; k++) {                                                  \
                acc0 = __builtin_amdgcn_mfma_f32_16x16x32_bf16(a[0][h * 4 + k], bf[k],     \
                                                               acc0, 0, 0, 0);             \
                acc1 = __builtin_amdgcn_mfma_f32_16x16x32_bf16(a[1][h * 4 + k], bf[k],     \
                                                               acc1, 0, 0, 0);             \
            }                                                                              \
        }                                                                                  \
        __builtin_amdgcn_s_setprio(0);                                                     \
        const int col = colbase + (ct_) * 16 + c16;                                        \
        _Pragma("unroll")                                                                  \
        for (int t = 0; t < 2; t++) {                                                      \
            const f32x4 acv = t ? acc1 : acc0;                                             \
            const int rw0 = rowbase + t * 16 + q * 4;                                      \
            _Pragma("unroll")                                                              \
            for (int r = 0; r < 4; r++) {                                                  \
                const float val = __expf(acv[r] * INV_TEMP);                               \
                tot[t][r] += val;                                                          \
                pos[t][r] += (((trow[t] >> (8 * r)) & 255) == ctid[(ct_)]) ? val : 0.f;    \
                if (wantdiag && col == rw0 + r) diag[col] = val;                           \
            }                                                                              \
        }                                                                                  \
    } while (0)

    // Prologue wait: FIFO vmcnt -- everything but the 4 newest retired, so
    // stage 0 (oldest) and the A panel are in. Barrier publishes all slices.
    WAITV(4); BAR();

    STAGE(3); COMPUTE(0); WAITV(4); BAR();   // in flight after wait: stages 2,3
    STAGE(4); COMPUTE(1); WAITV(4); BAR();
    STAGE(5); COMPUTE(2); WAITV(4); BAR();
    STAGE(6); COMPUTE(3); WAITV(4); BAR();
    STAGE(7); COMPUTE(4); WAITV(4); BAR();
    COMPUTE(5); WAITV(2); BAR();
    COMPUTE(6); WAITV(0); BAR();
    COMPUTE(7);

#undef COMPUTE
#undef STAGE
#undef WAITV
#undef BAR

    // Reduce across the 16 column-lanes sharing (q, r); one atomic per row.
#pragma unroll
    for (int t = 0; t < 2; t++)
#pragma unroll
        for (int r = 0; r < 4; r++) {
            float aS = tot[t][r], p = pos[t][r];
#pragma unroll
            for (int off = 1; off < 16; off <<= 1) {
                aS += __shfl_xor(aS, off);
                p  += __shfl_xor(p, off);
            }
            if (c16 == 0) {
                const int row = rowbase + t * 16 + q * 4 + r;
                atomicAdd(&Tot[row], aS);
                atomicAdd(mode ? &Pxx[row] : &Pxy[row], p);
            }
        }
}

// ------------------------------------------------ finalize (reads 32 KB only)
__global__ void finalize_kernel(const float* __restrict__ Tot, const float* __restrict__ Pxy,
                                const float* __restrict__ Pxx, const float* __restrict__ diag,
                                const int* __restrict__ tid, float* __restrict__ out) {
    __shared__ float num_s[TT], den_s[TT];
    __shared__ int cnt_s[TT];
    const int t = threadIdx.x;  // 256 threads
    num_s[t] = 0.f; den_s[t] = 0.f; cnt_s[t] = 0;
    __syncthreads();
    for (int i = t; i < NN; i += 256) {
        float tt_ = Tot[i], pxy = Pxy[i], pxx = Pxx[i];
        float num = pxy + 0.5f * (pxx - diag[i]);
        float den = tt_ - pxy - pxx;
        int tr = tid[i];
        atomicAdd(&num_s[tr], num);
        atomicAdd(&den_s[tr], den);
        atomicAdd(&cnt_s[tr], 1);
    }
    __syncthreads();
    float lt = 0.f, pr = 0.f;
    if (cnt_s[t] > 0) {
        lt = -logf(num_s[t] / (den_s[t] + num_s[t]));
        pr = 1.f;
    }
    for (int off = 32; off; off >>= 1) { lt += __shfl_down(lt, off); pr += __shfl_down(pr, off); }
    __shared__ float ls[4], ps[4];
    if ((t & 63) == 0) { ls[t >> 6] = lt; ps[t >> 6] = pr; }
    __syncthreads();
    if (t == 0) out[0] = (ls[0] + ls[1] + ls[2] + ls[3]) / (ps[0] + ps[1] + ps[2] + ps[3]);
}

// ------------------------------------------------ launch
extern "C" void kernel_launch(void* const* d_in, const int* in_sizes, int n_in,
                              void* d_out, int out_size, void* d_ws, size_t ws_size,
                              hipStream_t stream) {
    const float* x   = (const float*)d_in[0];
    const int*   tid = (const int*)d_in[1];
    const float* y   = (const float*)d_in[2];
    float* out = (float*)d_out;

    char* ws = (char*)d_ws;
    bf16x8* xfl = (bf16x8*)ws;                       // 1 MB frag-linear x
    bf16x8* yfl = (bf16x8*)(ws + (1u << 20));        // 8 MB frag-linear y
    float* acc  = (float*)(ws + 9u * (1u << 20));    // Tot,Pxy,Pxx,diag: 4*2048 f32
    float* Tot  = acc;
    float* Pxy  = acc + NN;
    float* Pxx  = acc + 2 * NN;
    float* diag = acc + 3 * NN;                      // fully rewritten by stats (mode 1)

    cvt_zero_kernel<<<2304, 256, 0, stream>>>(x, y, xfl, yfl, acc);
    stats_kernel<<<NROWBLK * (NCHUNK_XY + NCHUNK_XX), 256, 0, stream>>>(
        xfl, yfl, tid, Tot, Pxy, Pxx, diag);
    finalize_kernel<<<1, 256, 0, stream>>>(Tot, Pxy, Pxx, diag, tid, out);
}